// Round 1
// baseline (99.595 us; speedup 1.0000x reference)
//
#include <hip/hip_runtime.h>
#include <math.h>

#define T_LEN 2048
#define KNUM 10000
#define MAXKL 11
#define XP_PAD 3456          // covers max index 3413 (Ls=7, dil=341 case), multiple of 256
#define NB2 40               // classifier partial blocks
#define CHUNK2 500           // features per classifier block (40*500 = 20000 = 2K)
#define NCLS 10

// ---------------- Kernel 1: ROCKET features (ppv + max) ----------------
// One block per rocket kernel. x staged in LDS with left pad of 1 and
// zero-fill to XP_PAD so the fully-unrolled 11-tap loop never clamps:
// taps j >= Ls have w[j] == 0 exactly (input data is zero-masked), and the
// padded region is zero-filled (finite), so 0 * xp[big] == 0.
__global__ __launch_bounds__(256) void rocket_feats_kernel(
    const float* __restrict__ x, const float* __restrict__ w,
    const float* __restrict__ b, const int* __restrict__ dil,
    const int* __restrict__ pad, const int* __restrict__ Ls,
    float* __restrict__ feats)
{
    __shared__ float xp[XP_PAD];
    __shared__ float wmx[4];
    __shared__ int   wcnt[4];

    const int tid = threadIdx.x;
    const int k   = blockIdx.x;

    // stage signal: xp[0] = 0, xp[1..T] = x, rest = 0
    for (int i = tid; i < XP_PAD; i += 256) {
        const int src = i - 1;
        float v = 0.0f;
        if (src >= 0 && src < T_LEN) v = x[src];
        xp[i] = v;
    }

    // per-kernel params (block-uniform)
    float wr[MAXKL];
#pragma unroll
    for (int j = 0; j < MAXKL; ++j) wr[j] = w[k * MAXKL + j];
    const float bias = b[k];
    const int d  = dil[k];
    const int p  = pad[k];
    const int L  = Ls[k];
    const int out_len = T_LEN + 2 * p - d * (L - 1);   // >= 1 always
    const int s0 = 1 - p;

    __syncthreads();

    int   cnt = 0;
    float mx  = -INFINITY;
    for (int s = tid; s < out_len; s += 256) {
        const int base = s0 + s;
        float acc = bias;
#pragma unroll
        for (int j = 0; j < MAXKL; ++j)
            acc = fmaf(wr[j], xp[base + j * d], acc);
        cnt += (acc > 0.0f) ? 1 : 0;
        mx = fmaxf(mx, acc);
    }

    // wave reduce (64 lanes)
#pragma unroll
    for (int off = 32; off > 0; off >>= 1) {
        cnt += __shfl_down(cnt, off);
        mx = fmaxf(mx, __shfl_down(mx, off));
    }
    const int wave = tid >> 6;
    if ((tid & 63) == 0) { wmx[wave] = mx; wcnt[wave] = cnt; }
    __syncthreads();
    if (tid == 0) {
        float m = wmx[0];
        int   c = wcnt[0];
#pragma unroll
        for (int i = 1; i < 4; ++i) { m = fmaxf(m, wmx[i]); c += wcnt[i]; }
        feats[k]        = (float)c / (float)out_len;   // ppv
        feats[KNUM + k] = m;                           // max
    }
}

// ---------------- Kernel 2: partial GEMV feats @ Wc ----------------
__global__ __launch_bounds__(256) void rocket_logits_kernel(
    const float* __restrict__ feats, const float* __restrict__ Wc,
    float* __restrict__ partials)   // [NB2 * NCLS]
{
    float acc[NCLS];
#pragma unroll
    for (int c = 0; c < NCLS; ++c) acc[c] = 0.0f;

    const int fbeg = blockIdx.x * CHUNK2;
    const int fend = fbeg + CHUNK2;
    for (int f = fbeg + threadIdx.x; f < fend; f += 256) {
        const float v = feats[f];
        const float* __restrict__ wrow = Wc + (size_t)f * NCLS;
#pragma unroll
        for (int c = 0; c < NCLS; ++c)
            acc[c] = fmaf(v, wrow[c], acc[c]);
    }

    // reduce across 64-lane wave
#pragma unroll
    for (int c = 0; c < NCLS; ++c) {
#pragma unroll
        for (int off = 32; off > 0; off >>= 1)
            acc[c] += __shfl_down(acc[c], off);
    }
    __shared__ float lds[4][NCLS];
    const int wave = threadIdx.x >> 6;
    if ((threadIdx.x & 63) == 0) {
#pragma unroll
        for (int c = 0; c < NCLS; ++c) lds[wave][c] = acc[c];
    }
    __syncthreads();
    if (threadIdx.x == 0) {
#pragma unroll
        for (int c = 0; c < NCLS; ++c)
            partials[blockIdx.x * NCLS + c] =
                lds[0][c] + lds[1][c] + lds[2][c] + lds[3][c];
    }
}

// ---------------- Kernel 3: final reduce + bias + softmax ----------------
__global__ __launch_bounds__(64) void rocket_softmax_kernel(
    const float* __restrict__ partials, const float* __restrict__ bc,
    float* __restrict__ out)
{
    __shared__ float lg[NCLS];
    const int t = threadIdx.x;
    if (t < NCLS) {
        float s = bc[t];
        for (int i = 0; i < NB2; ++i) s += partials[i * NCLS + t];
        lg[t] = s;
    }
    __syncthreads();
    if (t == 0) {
        float m = lg[0];
#pragma unroll
        for (int i = 1; i < NCLS; ++i) m = fmaxf(m, lg[i]);
        float e[NCLS];
        float se = 0.0f;
#pragma unroll
        for (int i = 0; i < NCLS; ++i) { e[i] = expf(lg[i] - m); se += e[i]; }
        const float inv = 1.0f / se;
#pragma unroll
        for (int i = 0; i < NCLS; ++i) out[i] = e[i] * inv;
    }
}

extern "C" void kernel_launch(void* const* d_in, const int* in_sizes, int n_in,
                              void* d_out, int out_size, void* d_ws, size_t ws_size,
                              hipStream_t stream) {
    const float* x   = (const float*)d_in[0];
    const float* w   = (const float*)d_in[1];
    const float* b   = (const float*)d_in[2];
    const int*   dil = (const int*)d_in[3];
    const int*   pad = (const int*)d_in[4];
    const int*   Ls  = (const int*)d_in[5];
    const float* Wc  = (const float*)d_in[6];
    const float* bc  = (const float*)d_in[7];
    float* out = (float*)d_out;

    float* feats    = (float*)d_ws;                       // 2*KNUM floats
    float* partials = feats + 2 * KNUM;                   // NB2*NCLS floats

    rocket_feats_kernel<<<KNUM, 256, 0, stream>>>(x, w, b, dil, pad, Ls, feats);
    rocket_logits_kernel<<<NB2, 256, 0, stream>>>(feats, Wc, partials);
    rocket_softmax_kernel<<<1, 64, 0, stream>>>(partials, bc, out);
}